// Round 1
// baseline (1745.004 us; speedup 1.0000x reference)
//
#include <hip/hip_runtime.h>
#include <hip/hip_bf16.h>

typedef __attribute__((ext_vector_type(8))) short short8v;
typedef __attribute__((ext_vector_type(4))) short short4v;
typedef __attribute__((ext_vector_type(4))) float floatx4;

#define K_DIM   23232
#define BATCH   4096
#define BM      128
#define BN      176
#define BK      64
#define LDK     72          // padded LDS leading dim (elems)
#define N_PAD   528
#define N_REAL  520
#define KSPLIT  3
#define KITERS  121         // 363 BK-iters / 3

__device__ __forceinline__ float clamp01(float x) {
    return fminf(fmaxf(x, 0.0f), 1.0f);
}

// ---------------- Kernel 1: feature-transform GEMM (bf16 MFMA) --------------
// C_partial[z][m][n] = sum_{k in chunk z} F[m][k] * W[n][k]   (no bias)
// m in [0,8192): rows 0..4095 = features1, 4096..8191 = features2
__global__ __launch_bounds__(256) void ft_gemm(
    const float* __restrict__ f1, const float* __restrict__ f2,
    const float* __restrict__ ftw, float* __restrict__ part)
{
    __shared__ __align__(16) __hip_bfloat16 As[BM][LDK];
    __shared__ __align__(16) __hip_bfloat16 Bs[BN][LDK];

    const int t    = threadIdx.x;
    const int w    = t >> 6;
    const int lane = t & 63;
    const int quad = lane >> 4;
    const int l16  = lane & 15;

    const int n0 = blockIdx.x * BN;
    const int m0 = blockIdx.y * BM;
    const int z  = blockIdx.z;
    const int kBegin = z * KITERS * BK;
    const int kEnd   = kBegin + KITERS * BK;

    const float* __restrict__ srcA =
        (m0 < BATCH) ? (f1 + (size_t)m0 * K_DIM)
                     : (f2 + (size_t)(m0 - BATCH) * K_DIM);

    floatx4 acc[2][11];
#pragma unroll
    for (int i = 0; i < 2; ++i)
#pragma unroll
        for (int j = 0; j < 11; ++j)
            acc[i][j] = (floatx4){0.f, 0.f, 0.f, 0.f};

    for (int k0 = kBegin; k0 < kEnd; k0 += BK) {
        __syncthreads();
        // ---- stage A tile: 128 rows x 64 cols, fp32 -> bf16 ----
#pragma unroll
        for (int it = 0; it < 8; ++it) {
            int c   = t + it * 256;
            int row = c >> 4;
            int col = (c & 15) * 4;
            float4 v = *(const float4*)(srcA + (size_t)row * K_DIM + k0 + col);
            union { short4v s; __hip_bfloat16 h[4]; } u;
            u.h[0] = __float2bfloat16(v.x);
            u.h[1] = __float2bfloat16(v.y);
            u.h[2] = __float2bfloat16(v.z);
            u.h[3] = __float2bfloat16(v.w);
            *(short4v*)(&As[row][col]) = u.s;
        }
        // ---- stage B tile: 176 rows x 64 cols (zero-pad n >= 520) ----
#pragma unroll
        for (int it = 0; it < 11; ++it) {
            int c   = t + it * 256;
            int row = c >> 4;
            int col = (c & 15) * 4;
            int gn  = n0 + row;
            float4 v;
            if (gn < N_REAL)
                v = *(const float4*)(ftw + (size_t)gn * K_DIM + k0 + col);
            else
                v = make_float4(0.f, 0.f, 0.f, 0.f);
            union { short4v s; __hip_bfloat16 h[4]; } u;
            u.h[0] = __float2bfloat16(v.x);
            u.h[1] = __float2bfloat16(v.y);
            u.h[2] = __float2bfloat16(v.z);
            u.h[3] = __float2bfloat16(v.w);
            *(short4v*)(&Bs[row][col]) = u.s;
        }
        __syncthreads();
        // ---- compute: 2 k-steps of 32, 2 M-frags x 11 N-frags per wave ----
#pragma unroll
        for (int ks = 0; ks < BK; ks += 32) {
            short8v a0 = *(const short8v*)(&As[w * 32 + l16][ks + quad * 8]);
            short8v a1 = *(const short8v*)(&As[w * 32 + 16 + l16][ks + quad * 8]);
#pragma unroll
            for (int nf = 0; nf < 11; ++nf) {
                short8v b = *(const short8v*)(&Bs[nf * 16 + l16][ks + quad * 8]);
                acc[0][nf] = __builtin_amdgcn_mfma_f32_16x16x32_bf16(a0, b, acc[0][nf], 0, 0, 0);
                acc[1][nf] = __builtin_amdgcn_mfma_f32_16x16x32_bf16(a1, b, acc[1][nf], 0, 0, 0);
            }
        }
    }

    // ---- epilogue: C/D layout col = lane&15, row = quad*4 + r ----
    float* __restrict__ dst = part + (size_t)z * (8192ULL * N_PAD);
#pragma unroll
    for (int mi = 0; mi < 2; ++mi) {
#pragma unroll
        for (int nf = 0; nf < 11; ++nf) {
            int gn = n0 + nf * 16 + l16;
#pragma unroll
            for (int r = 0; r < 4; ++r) {
                int gm = m0 + w * 32 + mi * 16 + quad * 4 + r;
                dst[(size_t)gm * N_PAD + gn] = acc[mi][nf][r];
            }
        }
    }
}

// ---------------- Kernel 2: per-sample MLP tail -----------------------------
__global__ __launch_bounds__(256) void nnue_tail(
    const float* __restrict__ part,     // [3][8192][528] partial products
    const int*   __restrict__ bucket,   // [4096]
    const float* __restrict__ ft_b,     // [520]
    const float* __restrict__ h1_w,     // [128][1024]
    const float* __restrict__ h1_b,     // [128]
    const float* __restrict__ h2_w,     // [256][16]
    const float* __restrict__ h2_b,     // [256]
    const float* __restrict__ out_w,    // [8][32]
    const float* __restrict__ out_b,    // [8]
    float* __restrict__ out)            // [4096]
{
    const int m = blockIdx.x;
    const int b = bucket[m];
    const size_t sz = 8192ULL * N_PAD;

    __shared__ float ft[1024];
    __shared__ float h1s[16];

    const float* p1 = part + (size_t)m * N_PAD;            // a1 row (z=0)
    const float* p2 = part + (size_t)(m + BATCH) * N_PAD;   // a2 row (z=0)

    for (int i = threadIdx.x; i < 1024; i += 256) {
        const float* pr = (i < 512) ? p1 : p2;
        int ci = i & 511;
        float v = pr[ci] + pr[ci + sz] + pr[ci + 2 * sz] + ft_b[ci];
        ft[i] = clamp01(v);
    }
    __syncthreads();

    const int w    = threadIdx.x >> 6;
    const int lane = threadIdx.x & 63;

    // h1: wave w computes outputs 4w .. 4w+3 (each a 1024-elem dot)
#pragma unroll
    for (int i = 0; i < 4; ++i) {
        int row = b * 16 + w * 4 + i;
        const float* wr = h1_w + (size_t)row * 1024;
        float s = 0.f;
#pragma unroll
        for (int c = 0; c < 16; ++c)
            s += ft[c * 64 + lane] * wr[c * 64 + lane];
#pragma unroll
        for (int off = 32; off > 0; off >>= 1)
            s += __shfl_down(s, off);
        if (lane == 0) h1s[w * 4 + i] = clamp01(s + h1_b[row]);
    }
    __syncthreads();

    if (threadIdx.x < 32) {
        int i = threadIdx.x;
        const float* wr = h2_w + (size_t)(b * 32 + i) * 16;
        float s = h2_b[b * 32 + i];
#pragma unroll
        for (int j = 0; j < 16; ++j) s += wr[j] * h1s[j];
        float prod = clamp01(s) * out_w[b * 32 + i];
#pragma unroll
        for (int off = 16; off > 0; off >>= 1)
            prod += __shfl_down(prod, off);
        if (i == 0) {
            float v1 = p1[512 + b] + p1[512 + b + sz] + p1[512 + b + 2 * sz];
            float v2 = p2[512 + b] + p2[512 + b + sz] + p2[512 + b + 2 * sz];
            float psqt = 0.5f * (v1 - v2);   // ft_b cancels exactly
            out[m] = prod + out_b[b] + 0.25f * psqt;
        }
    }
}

extern "C" void kernel_launch(void* const* d_in, const int* in_sizes, int n_in,
                              void* d_out, int out_size, void* d_ws, size_t ws_size,
                              hipStream_t stream) {
    // setup_inputs order:
    // 0 bucket(i32) 1 features1 2 features2 3 ft_w 4 ft_b
    // 5 h1_w 6 h1_b 7 h2_w 8 h2_b 9 out_w 10 out_b
    const int*   bucket = (const int*)  d_in[0];
    const float* f1     = (const float*)d_in[1];
    const float* f2     = (const float*)d_in[2];
    const float* ftw    = (const float*)d_in[3];
    const float* ftb    = (const float*)d_in[4];
    const float* h1w    = (const float*)d_in[5];
    const float* h1b    = (const float*)d_in[6];
    const float* h2w    = (const float*)d_in[7];
    const float* h2b    = (const float*)d_in[8];
    const float* outw   = (const float*)d_in[9];
    const float* outb   = (const float*)d_in[10];
    float* out = (float*)d_out;

    float* part = (float*)d_ws;   // KSPLIT * 8192 * 528 floats = 51.9 MB

    dim3 grid1(3, 64, KSPLIT);
    ft_gemm<<<grid1, 256, 0, stream>>>(f1, f2, ftw, part);

    nnue_tail<<<BATCH, 256, 0, stream>>>(part, bucket, ftb, h1w, h1b,
                                         h2w, h2b, outw, outb, out);
}

// Round 2
// 1189.052 us; speedup vs baseline: 1.4676x; 1.4676x over previous
//
#include <hip/hip_runtime.h>
#include <hip/hip_bf16.h>
#include <stdint.h>

typedef __attribute__((ext_vector_type(8))) short short8v;
typedef __attribute__((ext_vector_type(4))) short short4v;
typedef __attribute__((ext_vector_type(4))) float floatx4;

#define K_DIM   23232
#define BATCH   4096
#define M_TOT   8192
#define BM      128
#define BN      176
#define BK      64
#define N_PAD   528
#define N_REAL  520

__device__ __forceinline__ float clamp01(float x) {
    return fminf(fmaxf(x, 0.0f), 1.0f);
}

__device__ __forceinline__ short8v cvt8(float4 a, float4 b) {
    union { short8v s; __hip_bfloat16 h[8]; } u;
    u.h[0] = __float2bfloat16(a.x); u.h[1] = __float2bfloat16(a.y);
    u.h[2] = __float2bfloat16(a.z); u.h[3] = __float2bfloat16(a.w);
    u.h[4] = __float2bfloat16(b.x); u.h[5] = __float2bfloat16(b.y);
    u.h[6] = __float2bfloat16(b.z); u.h[7] = __float2bfloat16(b.w);
    return u.s;
}

#define GLOAD_LDS16(g, l) __builtin_amdgcn_global_load_lds(               \
    (const __attribute__((address_space(1))) void*)(g),                   \
    (__attribute__((address_space(3))) void*)(l), 16, 0, 0)

// ------------- Kernel 0: fp32 -> bf16 pre-convert (pure BW) -----------------
// A[8192][23232] = [f1; f2],  B[528][23232] = [ftw; zeros(8 rows)]
__global__ __launch_bounds__(256) void convert_bf16(
    const float* __restrict__ f1, const float* __restrict__ f2,
    const float* __restrict__ ftw,
    __hip_bfloat16* __restrict__ A, __hip_bfloat16* __restrict__ B)
{
    const size_t totalA = (size_t)M_TOT * K_DIM;
    const size_t halfA  = totalA / 2;
    const size_t totalB = (size_t)N_PAD * K_DIM;
    const size_t realB  = (size_t)N_REAL * K_DIM;
    size_t idx    = ((size_t)blockIdx.x * blockDim.x + threadIdx.x) * 8;
    size_t stride = (size_t)gridDim.x * blockDim.x * 8;

    for (size_t i = idx; i < totalA; i += stride) {
        const float* src = (i < halfA) ? (f1 + i) : (f2 + (i - halfA));
        float4 v0 = *(const float4*)(src);
        float4 v1 = *(const float4*)(src + 4);
        *(short8v*)(A + i) = cvt8(v0, v1);
    }
    for (size_t i = idx; i < totalB; i += stride) {
        if (i < realB) {
            float4 v0 = *(const float4*)(ftw + i);
            float4 v1 = *(const float4*)(ftw + i + 4);
            *(short8v*)(B + i) = cvt8(v0, v1);
        } else {
            *(short8v*)(B + i) = (short8v){0,0,0,0,0,0,0,0};
        }
    }
}

// ------------- Kernel 1: bf16 MFMA GEMM with global_load_lds ----------------
// part[z][m][n] = sum_{k in chunk z} A[m][k] * B[n][k]
__global__ __launch_bounds__(256) void ft_gemm(
    const __hip_bfloat16* __restrict__ A,
    const __hip_bfloat16* __restrict__ B,
    float* __restrict__ part, int kiters)
{
    __shared__ __align__(16) __hip_bfloat16 As[BM][BK];   // 16 KB, no pad (DMA)
    __shared__ __align__(16) __hip_bfloat16 Bs[BN][BK];   // 22 KB

    const int t    = threadIdx.x;
    const int w    = t >> 6;
    const int lane = t & 63;
    const int quad = lane >> 4;
    const int l16  = lane & 15;

    const int n0 = blockIdx.x * BN;
    const int m0 = blockIdx.y * BM;
    const int z  = blockIdx.z;
    int k0 = z * kiters * BK;
    const int kEnd = k0 + kiters * BK;

    // DMA staging: lane l of a wave-issue covering rows R..R+7 loads
    // row R + (l>>3), col (l&7)*8 ; lands at LDS base + l*16.
    const int arow = lane >> 3;
    const int acol = (lane & 7) * 8;

    floatx4 acc[2][11];
#pragma unroll
    for (int i = 0; i < 2; ++i)
#pragma unroll
        for (int j = 0; j < 11; ++j)
            acc[i][j] = (floatx4){0.f, 0.f, 0.f, 0.f};

    for (; k0 < kEnd; k0 += BK) {
        __syncthreads();
        // stage A: 128 rows, 4 wave-issues per wave
#pragma unroll
        for (int i = 0; i < 4; ++i) {
            int R = w * 8 + i * 32;
            const __hip_bfloat16* g =
                A + (size_t)(m0 + R + arow) * K_DIM + k0 + acol;
            GLOAD_LDS16(g, &As[R][0]);
        }
        // stage B: 176 rows (6/6/5/5 issues across waves)
        for (int R = w * 8; R < BN; R += 32) {
            const __hip_bfloat16* g =
                B + (size_t)(n0 + R + arow) * K_DIM + k0 + acol;
            GLOAD_LDS16(g, &Bs[R][0]);
        }
        __syncthreads();
#pragma unroll
        for (int ks = 0; ks < BK; ks += 32) {
            short8v a0 = *(const short8v*)(&As[w * 32 + l16][ks + quad * 8]);
            short8v a1 = *(const short8v*)(&As[w * 32 + 16 + l16][ks + quad * 8]);
#pragma unroll
            for (int nf = 0; nf < 11; ++nf) {
                short8v b = *(const short8v*)(&Bs[nf * 16 + l16][ks + quad * 8]);
                acc[0][nf] = __builtin_amdgcn_mfma_f32_16x16x32_bf16(a0, b, acc[0][nf], 0, 0, 0);
                acc[1][nf] = __builtin_amdgcn_mfma_f32_16x16x32_bf16(a1, b, acc[1][nf], 0, 0, 0);
            }
        }
    }

    float* __restrict__ dst = part + (size_t)z * ((size_t)M_TOT * N_PAD);
#pragma unroll
    for (int mi = 0; mi < 2; ++mi) {
#pragma unroll
        for (int nf = 0; nf < 11; ++nf) {
            int gn = n0 + nf * 16 + l16;
#pragma unroll
            for (int r = 0; r < 4; ++r) {
                int gm = m0 + w * 32 + mi * 16 + quad * 4 + r;
                dst[(size_t)gm * N_PAD + gn] = acc[mi][nf][r];
            }
        }
    }
}

// ------------- Kernel 1 (fallback): fused-convert GEMM (round-1, proven) ----
__global__ __launch_bounds__(256) void ft_gemm_fused(
    const float* __restrict__ f1, const float* __restrict__ f2,
    const float* __restrict__ ftw, float* __restrict__ part, int kiters)
{
    __shared__ __align__(16) __hip_bfloat16 As[BM][72];
    __shared__ __align__(16) __hip_bfloat16 Bs[BN][72];

    const int t    = threadIdx.x;
    const int w    = t >> 6;
    const int lane = t & 63;
    const int quad = lane >> 4;
    const int l16  = lane & 15;

    const int n0 = blockIdx.x * BN;
    const int m0 = blockIdx.y * BM;
    const int z  = blockIdx.z;
    int k0 = z * kiters * BK;
    const int kEnd = k0 + kiters * BK;

    const float* __restrict__ srcA =
        (m0 < BATCH) ? (f1 + (size_t)m0 * K_DIM)
                     : (f2 + (size_t)(m0 - BATCH) * K_DIM);

    floatx4 acc[2][11];
#pragma unroll
    for (int i = 0; i < 2; ++i)
#pragma unroll
        for (int j = 0; j < 11; ++j)
            acc[i][j] = (floatx4){0.f, 0.f, 0.f, 0.f};

    for (; k0 < kEnd; k0 += BK) {
        __syncthreads();
#pragma unroll
        for (int it = 0; it < 8; ++it) {
            int c = t + it * 256, row = c >> 4, col = (c & 15) * 4;
            float4 v = *(const float4*)(srcA + (size_t)row * K_DIM + k0 + col);
            union { short4v s; __hip_bfloat16 h[4]; } u;
            u.h[0] = __float2bfloat16(v.x); u.h[1] = __float2bfloat16(v.y);
            u.h[2] = __float2bfloat16(v.z); u.h[3] = __float2bfloat16(v.w);
            *(short4v*)(&As[row][col]) = u.s;
        }
#pragma unroll
        for (int it = 0; it < 11; ++it) {
            int c = t + it * 256, row = c >> 4, col = (c & 15) * 4;
            int gn = n0 + row;
            float4 v = (gn < N_REAL)
                ? *(const float4*)(ftw + (size_t)gn * K_DIM + k0 + col)
                : make_float4(0.f, 0.f, 0.f, 0.f);
            union { short4v s; __hip_bfloat16 h[4]; } u;
            u.h[0] = __float2bfloat16(v.x); u.h[1] = __float2bfloat16(v.y);
            u.h[2] = __float2bfloat16(v.z); u.h[3] = __float2bfloat16(v.w);
            *(short4v*)(&Bs[row][col]) = u.s;
        }
        __syncthreads();
#pragma unroll
        for (int ks = 0; ks < BK; ks += 32) {
            short8v a0 = *(const short8v*)(&As[w * 32 + l16][ks + quad * 8]);
            short8v a1 = *(const short8v*)(&As[w * 32 + 16 + l16][ks + quad * 8]);
#pragma unroll
            for (int nf = 0; nf < 11; ++nf) {
                short8v b = *(const short8v*)(&Bs[nf * 16 + l16][ks + quad * 8]);
                acc[0][nf] = __builtin_amdgcn_mfma_f32_16x16x32_bf16(a0, b, acc[0][nf], 0, 0, 0);
                acc[1][nf] = __builtin_amdgcn_mfma_f32_16x16x32_bf16(a1, b, acc[1][nf], 0, 0, 0);
            }
        }
    }

    float* __restrict__ dst = part + (size_t)z * ((size_t)M_TOT * N_PAD);
#pragma unroll
    for (int mi = 0; mi < 2; ++mi) {
#pragma unroll
        for (int nf = 0; nf < 11; ++nf) {
            int gn = n0 + nf * 16 + l16;
#pragma unroll
            for (int r = 0; r < 4; ++r) {
                int gm = m0 + w * 32 + mi * 16 + quad * 4 + r;
                dst[(size_t)gm * N_PAD + gn] = acc[mi][nf][r];
            }
        }
    }
}

// ------------- Kernel 2: per-sample MLP tail --------------------------------
__global__ __launch_bounds__(256) void nnue_tail(
    const float* __restrict__ part, int ksplit,
    const int*   __restrict__ bucket,
    const float* __restrict__ ft_b,
    const float* __restrict__ h1_w, const float* __restrict__ h1_b,
    const float* __restrict__ h2_w, const float* __restrict__ h2_b,
    const float* __restrict__ out_w, const float* __restrict__ out_b,
    float* __restrict__ out)
{
    const int m = blockIdx.x;
    const int b = bucket[m];
    const size_t sz = (size_t)M_TOT * N_PAD;

    __shared__ float ft[1024];
    __shared__ float h1s[16];

    const float* p1 = part + (size_t)m * N_PAD;
    const float* p2 = part + (size_t)(m + BATCH) * N_PAD;

    for (int i = threadIdx.x; i < 1024; i += 256) {
        const float* pr = (i < 512) ? p1 : p2;
        int ci = i & 511;
        float v = ft_b[ci];
        for (int s = 0; s < ksplit; ++s) v += pr[ci + s * sz];
        ft[i] = clamp01(v);
    }
    __syncthreads();

    const int w    = threadIdx.x >> 6;
    const int lane = threadIdx.x & 63;

#pragma unroll
    for (int i = 0; i < 4; ++i) {
        int row = b * 16 + w * 4 + i;
        const float* wr = h1_w + (size_t)row * 1024;
        float s = 0.f;
#pragma unroll
        for (int c = 0; c < 16; ++c)
            s += ft[c * 64 + lane] * wr[c * 64 + lane];
#pragma unroll
        for (int off = 32; off > 0; off >>= 1)
            s += __shfl_down(s, off);
        if (lane == 0) h1s[w * 4 + i] = clamp01(s + h1_b[row]);
    }
    __syncthreads();

    if (threadIdx.x < 32) {
        int i = threadIdx.x;
        const float* wr = h2_w + (size_t)(b * 32 + i) * 16;
        float s = h2_b[b * 32 + i];
#pragma unroll
        for (int j = 0; j < 16; ++j) s += wr[j] * h1s[j];
        float prod = clamp01(s) * out_w[b * 32 + i];
#pragma unroll
        for (int off = 16; off > 0; off >>= 1)
            prod += __shfl_down(prod, off);
        if (i == 0) {
            float v1 = 0.f, v2 = 0.f;
            for (int s2 = 0; s2 < ksplit; ++s2) {
                v1 += p1[512 + b + s2 * sz];
                v2 += p2[512 + b + s2 * sz];
            }
            out[m] = prod + out_b[b] + 0.25f * 0.5f * 2.0f * (v1 - v2) * 0.5f
                   // simplify: 0.25 * psqt where psqt = 0.5*(v1-v2)
                   ;
        }
    }
}

// NOTE on the constant above: FV_SCALE * 2^FT_SHIFT / 2^SHIFT = 16/64 = 0.25,
// psqt = 0.5*(v1 - v2)  =>  out += 0.25 * 0.5 * (v1 - v2) = 0.125*(v1-v2).
// The expression above evaluates to 0.25*0.5*(v1-v2)*... — replaced below by
// a corrected kernel? No: 0.25f * 0.5f * 2.0f * (v1-v2) * 0.5f = 0.125*(v1-v2). OK.

extern "C" void kernel_launch(void* const* d_in, const int* in_sizes, int n_in,
                              void* d_out, int out_size, void* d_ws, size_t ws_size,
                              hipStream_t stream) {
    const int*   bucket = (const int*)  d_in[0];
    const float* f1     = (const float*)d_in[1];
    const float* f2     = (const float*)d_in[2];
    const float* ftw    = (const float*)d_in[3];
    const float* ftb    = (const float*)d_in[4];
    const float* h1w    = (const float*)d_in[5];
    const float* h1b    = (const float*)d_in[6];
    const float* h2w    = (const float*)d_in[7];
    const float* h2b    = (const float*)d_in[8];
    const float* outw   = (const float*)d_in[9];
    const float* outb   = (const float*)d_in[10];
    float* out = (float*)d_out;

    const size_t szA = (size_t)M_TOT * K_DIM * sizeof(__hip_bfloat16);
    const size_t szB = (size_t)N_PAD * K_DIM * sizeof(__hip_bfloat16);
    const size_t szPart1 = (size_t)M_TOT * N_PAD * sizeof(float);

    int ksplit;
    if (ws_size >= szA + szB + 11 * szPart1)      ksplit = 11;  // 33 k-iters
    else if (ws_size >= szA + szB + 3 * szPart1)  ksplit = 3;   // 121 k-iters
    else                                          ksplit = 0;   // fused fallback

    if (ksplit > 0) {
        __hip_bfloat16* A = (__hip_bfloat16*)d_ws;
        __hip_bfloat16* Bm = (__hip_bfloat16*)((char*)d_ws + szA);
        float* part = (float*)((char*)d_ws + szA + szB);
        int kiters = 363 / ksplit;

        convert_bf16<<<4096, 256, 0, stream>>>(f1, f2, ftw, A, Bm);
        dim3 grid1(3, 64, ksplit);
        ft_gemm<<<grid1, 256, 0, stream>>>(A, Bm, part, kiters);
        nnue_tail<<<BATCH, 256, 0, stream>>>(part, ksplit, bucket, ftb,
                                             h1w, h1b, h2w, h2b, outw, outb, out);
    } else {
        float* part = (float*)d_ws;
        dim3 grid1(3, 64, 3);
        ft_gemm_fused<<<grid1, 256, 0, stream>>>(f1, f2, ftw, part, 121);
        nnue_tail<<<BATCH, 256, 0, stream>>>(part, 3, bucket, ftb,
                                             h1w, h1b, h2w, h2b, outw, outb, out);
    }
}